// Round 10
// baseline (569.995 us; speedup 1.0000x reference)
//
#include <hip/hip_runtime.h>
#include <hip/hip_bf16.h>

using bf16 = __hip_bfloat16;

// Problem constants (from reference)
constexpr int kB = 4, kM = 64;
constexpr int kN2 = 512, kN1 = 2048, kN0 = 8192;
constexpr int kC2 = 256, kC1 = 128, kC0 = 64;

__device__ __forceinline__ float bf2f(bf16 v) { return __bfloat162float(v); }
__device__ __forceinline__ float rdIn(const void* p, long i, int f32) {
    return f32 ? ((const float*)p)[i] : bf2f(((const bf16*)p)[i]);
}

// ===========================================================================
// dtype probe on `pos` (uniform [0,1)): bf16 storage => every 16-bit half is
// a bf16 in [0,1]: sign clear, pattern <= 0x3F80. fp32 storage => low halves
// are random mantissa bits (bad w.p. ~0.75 each over 512 words) or all zero.
// writes flag: 1 = fp32, 0 = bf16.
// ===========================================================================
__global__ void fpno_probe_dtype(const unsigned int* __restrict__ w,
                                 int* __restrict__ flag) {
    __shared__ int sBad, sNz;
    if (threadIdx.x == 0) { sBad = 0; sNz = 0; }
    __syncthreads();
    int bad = 0, nz = 0;
    for (int j = 0; j < 2; j++) {
        unsigned lo = w[threadIdx.x + 256 * j] & 0xFFFFu;  // words 0..511 < 3072
        if (lo != 0u) { nz = 1; if ((lo & 0x8000u) || lo > 0x3F80u) bad = 1; }
    }
    if (bad) sBad = 1;
    if (nz) sNz = 1;
    __syncthreads();
    if (threadIdx.x == 0) *flag = (sBad || !sNz) ? 1 : 0;
}

// ===========================================================================
// per-sample gate vectors: g0[b][n] = tanh(par[b] @ Wp0 + bp0)[n]; g1 likewise
// ===========================================================================
__global__ void fpno_gates(const void* __restrict__ par,
                           const void* __restrict__ Wp0, const void* __restrict__ bp0,
                           const void* __restrict__ Wp1, const void* __restrict__ bp1,
                           const int* __restrict__ flagp,
                           float* __restrict__ g0, float* __restrict__ g1) {
    const int f32 = *flagp;
    int id = blockIdx.x * 256 + threadIdx.x;
    if (id < kB * 128) {
        int b = id / 128, n = id % 128;
        float a = rdIn(bp0, n, f32);
        for (int m = 0; m < kM; m++)
            a += rdIn(par, b * kM + m, f32) * rdIn(Wp0, m * 128 + n, f32);
        g0[id] = tanhf(a);
    } else if (id < kB * 128 + kB * 64) {
        int id2 = id - kB * 128;
        int b = id2 / 64, n = id2 % 64;
        float a = rdIn(bp1, n, f32);
        for (int m = 0; m < kM; m++)
            a += rdIn(par, b * kM + m, f32) * rdIn(Wp1, m * 64 + n, f32);
        g1[id2] = tanhf(a);
    }
}

// ===========================================================================
// kNN, k=3: one thread per target, per-sample source tile staged in LDS.
// fp contract OFF so d = ((dx*dx)+(dy*dy))+(dz*dz) matches np's non-FMA eval.
// Strict '<' insertion keeps the earliest index on ties (lax.top_k order).
// Emits global indices and normalized inverse-square-distance weights (fp32).
// ===========================================================================
template <int NS>
__global__ void fpno_nn3(const void* __restrict__ srcP, const void* __restrict__ tgtP,
                         const int* __restrict__ flagp, int tgtPerSample,
                         int* __restrict__ oIdx, float* __restrict__ oW) {
    #pragma clang fp contract(off)
    __shared__ float4 sp[NS];
    const int f32 = *flagp;
    int t = blockIdx.x * 256 + threadIdx.x;
    int smp = t / tgtPerSample;  // 256 | tgtPerSample: no block straddles samples
    for (int i = threadIdx.x; i < NS; i += 256) {
        long b = (long)(smp * NS + i) * 3;
        sp[i] = make_float4(rdIn(srcP, b, f32), rdIn(srcP, b + 1, f32),
                            rdIn(srcP, b + 2, f32), 0.f);
    }
    __syncthreads();
    long tb = (long)t * 3;
    float px = rdIn(tgtP, tb, f32), py = rdIn(tgtP, tb + 1, f32),
          pz = rdIn(tgtP, tb + 2, f32);
    float d0 = 1e30f, d1 = 1e30f, d2 = 1e30f;
    int i0 = 0, i1 = 0, i2 = 0;
    for (int j = 0; j < NS; j++) {
        float4 s = sp[j];
        float dx = px - s.x, dy = py - s.y, dz = pz - s.z;
        float d = ((dx * dx) + (dy * dy)) + (dz * dz);
        if (d < d2) {
            if (d < d1) {
                d2 = d1; i2 = i1;
                if (d < d0) { d1 = d0; i1 = i0; d0 = d; i0 = j; }
                else        { d1 = d;  i1 = j; }
            } else { d2 = d; i2 = j; }
        }
    }
    float wa = 1.f / fmaxf(d0, 1e-16f);
    float wb = 1.f / fmaxf(d1, 1e-16f);
    float wc = 1.f / fmaxf(d2, 1e-16f);
    float s = wa + wb + wc;
    oIdx[t * 3 + 0] = smp * NS + i0;
    oIdx[t * 3 + 1] = smp * NS + i1;
    oIdx[t * 3 + 2] = smp * NS + i2;
    oW[t * 3 + 0] = wa / s;
    oW[t * 3 + 1] = wb / s;
    oW[t * 3 + 2] = wc / s;
}

// ===========================================================================
// stage-A GEMM: H[M, Nd] = tanh( Xcat @ W + b ), Xcat built on the fly:
//   col kk < CF : interpolated features (3-gather, fp32 weights)
//   col kk >= CF: skip features
// feats source: featsF (fp32 ws) if non-null, else feats_raw (flag dtype).
// 64x64 tile, 4x4/thread, all-fp32 LDS and output.
// ===========================================================================
template <int CF, int CS>
__global__ void fpno_stage_a(const void* __restrict__ feats_raw,
                             const float* __restrict__ featsF,
                             const void* __restrict__ skip_raw,
                             const void* __restrict__ W, const void* __restrict__ bv,
                             const int* __restrict__ idx, const float* __restrict__ wgt,
                             const int* __restrict__ flagp,
                             float* __restrict__ H, int Nd) {
    constexpr int KD = CF + CS;
    __shared__ float As[64][17];
    __shared__ float Bs[16][65];
    const int f32 = *flagp;
    const int tid = threadIdx.x;
    const int tx = tid & 15, ty = tid >> 4;
    const int bm = blockIdx.x, bn = blockIdx.y;
    float acc[4][4] = {};
    for (int k0 = 0; k0 < KD; k0 += 16) {
        #pragma unroll
        for (int l = 0; l < 4; l++) {
            int e = tid + l * 256;
            int m = e >> 4, k = e & 15;
            int kk = k0 + k;
            int rg = bm * 64 + m;
            float v;
            if (kk < CF) {
                int j0 = idx[rg * 3 + 0], j1 = idx[rg * 3 + 1], j2 = idx[rg * 3 + 2];
                float w0 = wgt[rg * 3 + 0], w1 = wgt[rg * 3 + 1], w2 = wgt[rg * 3 + 2];
                if (featsF) {
                    v = w0 * featsF[(long)j0 * CF + kk] + w1 * featsF[(long)j1 * CF + kk]
                      + w2 * featsF[(long)j2 * CF + kk];
                } else {
                    v = w0 * rdIn(feats_raw, (long)j0 * CF + kk, f32)
                      + w1 * rdIn(feats_raw, (long)j1 * CF + kk, f32)
                      + w2 * rdIn(feats_raw, (long)j2 * CF + kk, f32);
                }
            } else {
                v = rdIn(skip_raw, (long)rg * CS + (kk - CF), f32);
            }
            As[m][k] = v;
        }
        #pragma unroll
        for (int l = 0; l < 4; l++) {
            int e = tid + l * 256;
            int k = e >> 6, n = e & 63;
            Bs[k][n] = rdIn(W, (long)(k0 + k) * Nd + bn * 64 + n, f32);
        }
        __syncthreads();
        #pragma unroll
        for (int k = 0; k < 16; k++) {
            float a[4], b[4];
            #pragma unroll
            for (int i = 0; i < 4; i++) a[i] = As[ty * 4 + i][k];
            #pragma unroll
            for (int j = 0; j < 4; j++) b[j] = Bs[k][tx * 4 + j];
            #pragma unroll
            for (int i = 0; i < 4; i++)
                #pragma unroll
                for (int j = 0; j < 4; j++) acc[i][j] += a[i] * b[j];
        }
        __syncthreads();
    }
    #pragma unroll
    for (int i = 0; i < 4; i++) {
        int r = bm * 64 + ty * 4 + i;
        #pragma unroll
        for (int j = 0; j < 4; j++) {
            int c = bn * 64 + tx * 4 + j;
            H[(long)r * Nd + c] = tanhf(acc[i][j] + rdIn(bv, c, f32));
        }
    }
}

// ===========================================================================
// stage-B GEMM: Y = act(H @ W + b) * gate, H fp32 in ws, Y fp32 ALWAYS
// (d_out is a float32 buffer — the round-9 diagnosis: outputs are fp32,
//  writing bf16 aliased batch constants into the x0 chunk = absmax 3.373047).
// gate[(r >> SMPSHIFT) * Nd + c] (per-sample vector).
// ===========================================================================
template <bool TANH, int SMPSHIFT>
__global__ void fpno_stage_b(const float* __restrict__ Hs,
                             const void* __restrict__ W, const void* __restrict__ bv,
                             const float* __restrict__ gate, const int* __restrict__ flagp,
                             float* __restrict__ Y, int Kd, int Nd) {
    __shared__ float As[64][17];
    __shared__ float Bs[16][65];
    const int f32 = *flagp;
    const int tid = threadIdx.x;
    const int tx = tid & 15, ty = tid >> 4;
    const int bm = blockIdx.x, bn = blockIdx.y;
    float acc[4][4] = {};
    for (int k0 = 0; k0 < Kd; k0 += 16) {
        #pragma unroll
        for (int l = 0; l < 4; l++) {
            int e = tid + l * 256;
            int m = e >> 4, k = e & 15;
            As[m][k] = Hs[(long)(bm * 64 + m) * Kd + k0 + k];
        }
        #pragma unroll
        for (int l = 0; l < 4; l++) {
            int e = tid + l * 256;
            int k = e >> 6, n = e & 63;
            Bs[k][n] = rdIn(W, (long)(k0 + k) * Nd + bn * 64 + n, f32);
        }
        __syncthreads();
        #pragma unroll
        for (int k = 0; k < 16; k++) {
            float a[4], b[4];
            #pragma unroll
            for (int i = 0; i < 4; i++) a[i] = As[ty * 4 + i][k];
            #pragma unroll
            for (int j = 0; j < 4; j++) b[j] = Bs[k][tx * 4 + j];
            #pragma unroll
            for (int i = 0; i < 4; i++)
                #pragma unroll
                for (int j = 0; j < 4; j++) acc[i][j] += a[i] * b[j];
        }
        __syncthreads();
    }
    #pragma unroll
    for (int i = 0; i < 4; i++) {
        int r = bm * 64 + ty * 4 + i;
        #pragma unroll
        for (int j = 0; j < 4; j++) {
            int c = bn * 64 + tx * 4 + j;
            float v = acc[i][j] + rdIn(bv, c, f32);
            if (TANH) v = tanhf(v);
            v *= gate[(r >> SMPSHIFT) * Nd + c];
            Y[(long)r * Nd + c] = v;
        }
    }
}

// ===========================================================================
// output tail (fp32): [pos_skip_l0 (32768*3) | batch_skip_l0 (32768)]
// ===========================================================================
__global__ void fpno_tail(const void* __restrict__ pos0, const int* __restrict__ bt0,
                          const int* __restrict__ flagp, float* __restrict__ out) {
    const int f32 = *flagp;
    int id = blockIdx.x * 256 + threadIdx.x;  // 0..131071
    const int nX = kB * kN0 * kC0;   // 2097152
    const int nP = kB * kN0 * 3;     // 98304
    if (id < nP) out[nX + id] = rdIn(pos0, id, f32);
    else         out[nX + id] = (float)bt0[id - nP];
}

__global__ void fpno_guard(float code, float* __restrict__ out) {
    if (threadIdx.x == 0) out[0] = code;
}

// ===========================================================================
extern "C" void kernel_launch(void* const* d_in, const int* in_sizes, int n_in,
                              void* d_out, int out_size, void* d_ws, size_t ws_size,
                              hipStream_t stream) {
    (void)out_size;
    float* out = (float*)d_out;   // fp32 output buffer (round-9 diagnosis)
    const int R1 = kB * kN1;  // 8192
    const int R0 = kB * kN0;  // 32768

    static const int kExp[22] = {
        256, 524288, 6144, 2048, 1048576, 24576, 8192, 2097152, 98304, 32768,
        98304, 256, 32768, 128, 8192, 128, 24576, 128, 8192, 64, 4096, 64};
    if (n_in != 22) { fpno_guard<<<1, 64, 0, stream>>>(3072.0f, out); return; }
    for (int i = 0; i < 22; i++) {
        if (in_sizes[i] != kExp[i]) {
            fpno_guard<<<1, 64, 0, stream>>>(1024.0f + 8.0f * i, out);
            return;
        }
    }

    // ---- fp32 workspace (~29.3 MB) ----
    char* base = (char*)d_ws;
    size_t off = 0;
    auto alloc = [&](size_t bytes) {
        off = (off + 255) & ~(size_t)255; size_t o = off; off += bytes; return o;
    };
    int*   flag = (int*)(base + alloc(4));
    float* g0   = (float*)(base + alloc(kB * 128 * 4));
    float* g1   = (float*)(base + alloc(kB * 64 * 4));
    int*   i1d  = (int*)(base + alloc((size_t)R1 * 3 * 4));
    float* w1d  = (float*)(base + alloc((size_t)R1 * 3 * 4));
    int*   i0d  = (int*)(base + alloc((size_t)R0 * 3 * 4));
    float* w0d  = (float*)(base + alloc((size_t)R0 * 3 * 4));
    float* H1   = (float*)(base + alloc((size_t)R1 * 256 * 4));  // 8 MB
    float* X1   = (float*)(base + alloc((size_t)R1 * 128 * 4));  // 4 MB
    float* H2   = (float*)(base + alloc((size_t)R0 * 128 * 4));  // 16 MB
    if (ws_size < off) { fpno_guard<<<1, 64, 0, stream>>>(2048.0f, out); return; }

    const void* par  = d_in[0];
    const void* x    = d_in[1];
    const void* pos  = d_in[2];
    const void* xs1  = d_in[4];
    const void* pos1 = d_in[5];
    const void* xs0  = d_in[7];
    const void* pos0 = d_in[8];
    const int*  bt0  = (const int*)d_in[9];
    const void *W0a = d_in[10], *b0a = d_in[11], *W0b = d_in[12], *b0b = d_in[13];
    const void *Wp0 = d_in[14], *bp0 = d_in[15];
    const void *W1a = d_in[16], *b1a = d_in[17], *W1b = d_in[18], *b1b = d_in[19];
    const void *Wp1 = d_in[20], *bp1 = d_in[21];

    // 1) input dtype probe
    fpno_probe_dtype<<<1, 256, 0, stream>>>((const unsigned int*)pos, flag);

    // 2) per-sample gates
    fpno_gates<<<3, 256, 0, stream>>>(par, Wp0, bp0, Wp1, bp1, flag, g0, g1);

    // 3) layer-1 kNN: src pos (512/s) -> tgt pos_skip_l1 (2048/s)
    fpno_nn3<kN2><<<R1 / 256, 256, 0, stream>>>(pos, pos1, flag, kN1, i1d, w1d);

    // 4) H1 = tanh([interp(x), xs1] @ W0a + b0a)    8192x384 @ 384x256
    fpno_stage_a<kC2, kC1><<<dim3(R1 / 64, 4), 256, 0, stream>>>(
        x, nullptr, xs1, W0a, b0a, i1d, w1d, flag, H1, 256);

    // 5) X1 = tanh(H1 @ W0b + b0b) * g0             8192x256 @ 256x128, fp32
    fpno_stage_b<true, 11><<<dim3(R1 / 64, 2), 256, 0, stream>>>(
        H1, W0b, b0b, g0, flag, X1, 256, 128);

    // 6) layer-2 kNN: src pos_skip_l1 (2048/s) -> tgt pos_skip_l0 (8192/s)
    fpno_nn3<kN1><<<R0 / 256, 256, 0, stream>>>(pos1, pos0, flag, kN0, i0d, w0d);

    // 7) H2 = tanh([interp(X1), xs0] @ W1a + b1a)   32768x192 @ 192x128
    fpno_stage_a<kC1, kC0><<<dim3(R0 / 64, 2), 256, 0, stream>>>(
        nullptr, X1, xs0, W1a, b1a, i0d, w0d, flag, H2, 128);

    // 8) x0 = (H2 @ W1b + b1b) * g1 -> fp32 out     32768x128 @ 128x64
    fpno_stage_b<false, 13><<<dim3(R0 / 64, 1), 256, 0, stream>>>(
        H2, W1b, b1b, g1, flag, out, 128, 64);

    // 9) tail passthrough (fp32)
    fpno_tail<<<(kB * kN0 * 4) / 256, 256, 0, stream>>>(pos0, bt0, flag, out);
}

// Round 11
// 386.862 us; speedup vs baseline: 1.4734x; 1.4734x over previous
//
#include <hip/hip_runtime.h>
#include <hip/hip_bf16.h>

using bf16 = __hip_bfloat16;

// Problem constants (from reference)
constexpr int kB = 4, kM = 64;
constexpr int kN2 = 512, kN1 = 2048, kN0 = 8192;
constexpr int kC2 = 256, kC1 = 128, kC0 = 64;

__device__ __forceinline__ float bf2f(bf16 v) { return __bfloat162float(v); }
__device__ __forceinline__ float rdIn(const void* p, long i, int f32) {
    return f32 ? ((const float*)p)[i] : bf2f(((const bf16*)p)[i]);
}

// ===========================================================================
// dtype probe on `pos` (uniform [0,1)): bf16 storage => every 16-bit half is
// a bf16 in [0,1]. fp32 => low halves random mantissa bits (or all zero).
// flag: 1 = fp32, 0 = bf16.
// ===========================================================================
__global__ void fpno_probe_dtype(const unsigned int* __restrict__ w,
                                 int* __restrict__ flag) {
    __shared__ int sBad, sNz;
    if (threadIdx.x == 0) { sBad = 0; sNz = 0; }
    __syncthreads();
    int bad = 0, nz = 0;
    for (int j = 0; j < 2; j++) {
        unsigned lo = w[threadIdx.x + 256 * j] & 0xFFFFu;  // words 0..511 < 3072
        if (lo != 0u) { nz = 1; if ((lo & 0x8000u) || lo > 0x3F80u) bad = 1; }
    }
    if (bad) sBad = 1;
    if (nz) sNz = 1;
    __syncthreads();
    if (threadIdx.x == 0) *flag = (sBad || !sNz) ? 1 : 0;
}

// ===========================================================================
// per-sample gate vectors: g0[b][n] = tanh(par[b] @ Wp0 + bp0)[n]; g1 likewise
// ===========================================================================
__global__ void fpno_gates(const void* __restrict__ par,
                           const void* __restrict__ Wp0, const void* __restrict__ bp0,
                           const void* __restrict__ Wp1, const void* __restrict__ bp1,
                           const int* __restrict__ flagp,
                           float* __restrict__ g0, float* __restrict__ g1) {
    const int f32 = *flagp;
    int id = blockIdx.x * 256 + threadIdx.x;
    if (id < kB * 128) {
        int b = id / 128, n = id % 128;
        float a = rdIn(bp0, n, f32);
        for (int m = 0; m < kM; m++)
            a += rdIn(par, b * kM + m, f32) * rdIn(Wp0, m * 128 + n, f32);
        g0[id] = tanhf(a);
    } else if (id < kB * 128 + kB * 64) {
        int id2 = id - kB * 128;
        int b = id2 / 64, n = id2 % 64;
        float a = rdIn(bp1, n, f32);
        for (int m = 0; m < kM; m++)
            a += rdIn(par, b * kM + m, f32) * rdIn(Wp1, m * 64 + n, f32);
        g1[id2] = tanhf(a);
    }
}

// ===========================================================================
// kNN k=3, split-scan: 32 targets/block x SPLIT=8 scanner threads per target.
// Round-10 profile: old 1-thread-per-target kernel was 195 us at 5.7%
// occupancy (128 blocks, 2048-deep serial chain). Split-scan gives 8x blocks
// and 8x shorter chains. Selection is bit-identical to the serial scan:
// same FP distance ops (contract off, non-FMA), strict '<' within a split's
// increasing-index stream, and an explicit (d, index) tie-break at merge.
// In-wave layout: lane = 8*targetLocal + split -> at iter i the wave reads 8
// distinct float4s (banks 4s..4s+3, s=0..7) with 8-way broadcast: conflict-free.
// ===========================================================================
template <int NS>
__global__ void fpno_nn3s(const void* __restrict__ srcP, const void* __restrict__ tgtP,
                          const int* __restrict__ flagp, int tgtPerSample,
                          int* __restrict__ oIdx, float* __restrict__ oW) {
    #pragma clang fp contract(off)
    constexpr int SPLIT = 8;
    constexpr int TPB = 256 / SPLIT;  // 32 targets per block (32 | tgtPerSample)
    __shared__ float4 sp[NS];
    __shared__ float cd[256 * 3];
    __shared__ int   ci[256 * 3];
    const int f32 = *flagp;
    const int tid = threadIdx.x;
    const int tLoc = tid >> 3;        // 0..31
    const int spl  = tid & 7;         // 0..7
    const int tGlob = blockIdx.x * TPB + tLoc;
    const int smp = tGlob / tgtPerSample;   // uniform across block
    for (int i = tid; i < NS; i += 256) {
        long b = (long)(smp * NS + i) * 3;
        sp[i] = make_float4(rdIn(srcP, b, f32), rdIn(srcP, b + 1, f32),
                            rdIn(srcP, b + 2, f32), 0.f);
    }
    __syncthreads();
    long tb = (long)tGlob * 3;
    float px = rdIn(tgtP, tb, f32), py = rdIn(tgtP, tb + 1, f32),
          pz = rdIn(tgtP, tb + 2, f32);
    float d0 = 1e30f, d1 = 1e30f, d2 = 1e30f;
    int i0 = 0x7FFFFFFF, i1 = 0x7FFFFFFF, i2 = 0x7FFFFFFF;
    for (int j = spl; j < NS; j += SPLIT) {
        float4 s = sp[j];
        float dx = px - s.x, dy = py - s.y, dz = pz - s.z;
        float d = ((dx * dx) + (dy * dy)) + (dz * dz);
        bool l0 = d < d0, l1 = d < d1, l2 = d < d2;
        float nd2 = l1 ? d1 : (l2 ? d : d2);
        int   ni2 = l1 ? i1 : (l2 ? j : i2);
        float nd1 = l0 ? d0 : (l1 ? d : d1);
        int   ni1 = l0 ? i0 : (l1 ? j : i1);
        float nd0 = l0 ? d : d0;
        int   ni0 = l0 ? j : i0;
        d2 = nd2; i2 = ni2; d1 = nd1; i1 = ni1; d0 = nd0; i0 = ni0;
    }
    cd[tid * 3 + 0] = d0; ci[tid * 3 + 0] = i0;
    cd[tid * 3 + 1] = d1; ci[tid * 3 + 1] = i1;
    cd[tid * 3 + 2] = d2; ci[tid * 3 + 2] = i2;
    __syncthreads();
    if (spl == 0) {
        float b0 = 1e30f, b1 = 1e30f, b2 = 1e30f;
        int k0 = 0x7FFFFFFF, k1 = 0x7FFFFFFF, k2 = 0x7FFFFFFF;
        int qb = tLoc * SPLIT * 3;
        for (int q = 0; q < SPLIT * 3; q++) {
            float d = cd[qb + q];
            int i = ci[qb + q];
            if ((d < b2) || (d == b2 && i < k2)) {
                if ((d < b1) || (d == b1 && i < k1)) {
                    b2 = b1; k2 = k1;
                    if ((d < b0) || (d == b0 && i < k0)) { b1 = b0; k1 = k0; b0 = d; k0 = i; }
                    else                                  { b1 = d;  k1 = i; }
                } else { b2 = d; k2 = i; }
            }
        }
        float wa = 1.f / fmaxf(b0, 1e-16f);
        float wb = 1.f / fmaxf(b1, 1e-16f);
        float wc = 1.f / fmaxf(b2, 1e-16f);
        float s = wa + wb + wc;
        oIdx[tGlob * 3 + 0] = smp * NS + k0;
        oIdx[tGlob * 3 + 1] = smp * NS + k1;
        oIdx[tGlob * 3 + 2] = smp * NS + k2;
        oW[tGlob * 3 + 0] = wa / s;
        oW[tGlob * 3 + 1] = wb / s;
        oW[tGlob * 3 + 2] = wc / s;
    }
}

// ===========================================================================
// stage-A GEMM: H[M, Nd] = tanh( Xcat @ W + b ), Xcat built on the fly:
//   col kk < CF : interpolated features (3-gather, fp32 weights)
//   col kk >= CF: skip features
// feats source: featsF (fp32 ws) if non-null, else feats_raw (flag dtype).
// 64x64 tile, 4x4/thread, all-fp32 LDS and output.
// ===========================================================================
template <int CF, int CS>
__global__ void fpno_stage_a(const void* __restrict__ feats_raw,
                             const float* __restrict__ featsF,
                             const void* __restrict__ skip_raw,
                             const void* __restrict__ W, const void* __restrict__ bv,
                             const int* __restrict__ idx, const float* __restrict__ wgt,
                             const int* __restrict__ flagp,
                             float* __restrict__ H, int Nd) {
    constexpr int KD = CF + CS;
    __shared__ float As[64][17];
    __shared__ float Bs[16][65];
    const int f32 = *flagp;
    const int tid = threadIdx.x;
    const int tx = tid & 15, ty = tid >> 4;
    const int bm = blockIdx.x, bn = blockIdx.y;
    float acc[4][4] = {};
    for (int k0 = 0; k0 < KD; k0 += 16) {
        #pragma unroll
        for (int l = 0; l < 4; l++) {
            int e = tid + l * 256;
            int m = e >> 4, k = e & 15;
            int kk = k0 + k;
            int rg = bm * 64 + m;
            float v;
            if (kk < CF) {
                int j0 = idx[rg * 3 + 0], j1 = idx[rg * 3 + 1], j2 = idx[rg * 3 + 2];
                float w0 = wgt[rg * 3 + 0], w1 = wgt[rg * 3 + 1], w2 = wgt[rg * 3 + 2];
                if (featsF) {
                    v = w0 * featsF[(long)j0 * CF + kk] + w1 * featsF[(long)j1 * CF + kk]
                      + w2 * featsF[(long)j2 * CF + kk];
                } else {
                    v = w0 * rdIn(feats_raw, (long)j0 * CF + kk, f32)
                      + w1 * rdIn(feats_raw, (long)j1 * CF + kk, f32)
                      + w2 * rdIn(feats_raw, (long)j2 * CF + kk, f32);
                }
            } else {
                v = rdIn(skip_raw, (long)rg * CS + (kk - CF), f32);
            }
            As[m][k] = v;
        }
        #pragma unroll
        for (int l = 0; l < 4; l++) {
            int e = tid + l * 256;
            int k = e >> 6, n = e & 63;
            Bs[k][n] = rdIn(W, (long)(k0 + k) * Nd + bn * 64 + n, f32);
        }
        __syncthreads();
        #pragma unroll
        for (int k = 0; k < 16; k++) {
            float a[4], b[4];
            #pragma unroll
            for (int i = 0; i < 4; i++) a[i] = As[ty * 4 + i][k];
            #pragma unroll
            for (int j = 0; j < 4; j++) b[j] = Bs[k][tx * 4 + j];
            #pragma unroll
            for (int i = 0; i < 4; i++)
                #pragma unroll
                for (int j = 0; j < 4; j++) acc[i][j] += a[i] * b[j];
        }
        __syncthreads();
    }
    #pragma unroll
    for (int i = 0; i < 4; i++) {
        int r = bm * 64 + ty * 4 + i;
        #pragma unroll
        for (int j = 0; j < 4; j++) {
            int c = bn * 64 + tx * 4 + j;
            H[(long)r * Nd + c] = tanhf(acc[i][j] + rdIn(bv, c, f32));
        }
    }
}

// ===========================================================================
// stage-B GEMM: Y = act(H @ W + b) * gate, H fp32 in ws, Y fp32 ALWAYS
// (d_out is a float32 buffer). gate[(r >> SMPSHIFT) * Nd + c].
// ===========================================================================
template <bool TANH, int SMPSHIFT>
__global__ void fpno_stage_b(const float* __restrict__ Hs,
                             const void* __restrict__ W, const void* __restrict__ bv,
                             const float* __restrict__ gate, const int* __restrict__ flagp,
                             float* __restrict__ Y, int Kd, int Nd) {
    __shared__ float As[64][17];
    __shared__ float Bs[16][65];
    const int f32 = *flagp;
    const int tid = threadIdx.x;
    const int tx = tid & 15, ty = tid >> 4;
    const int bm = blockIdx.x, bn = blockIdx.y;
    float acc[4][4] = {};
    for (int k0 = 0; k0 < Kd; k0 += 16) {
        #pragma unroll
        for (int l = 0; l < 4; l++) {
            int e = tid + l * 256;
            int m = e >> 4, k = e & 15;
            As[m][k] = Hs[(long)(bm * 64 + m) * Kd + k0 + k];
        }
        #pragma unroll
        for (int l = 0; l < 4; l++) {
            int e = tid + l * 256;
            int k = e >> 6, n = e & 63;
            Bs[k][n] = rdIn(W, (long)(k0 + k) * Nd + bn * 64 + n, f32);
        }
        __syncthreads();
        #pragma unroll
        for (int k = 0; k < 16; k++) {
            float a[4], b[4];
            #pragma unroll
            for (int i = 0; i < 4; i++) a[i] = As[ty * 4 + i][k];
            #pragma unroll
            for (int j = 0; j < 4; j++) b[j] = Bs[k][tx * 4 + j];
            #pragma unroll
            for (int i = 0; i < 4; i++)
                #pragma unroll
                for (int j = 0; j < 4; j++) acc[i][j] += a[i] * b[j];
        }
        __syncthreads();
    }
    #pragma unroll
    for (int i = 0; i < 4; i++) {
        int r = bm * 64 + ty * 4 + i;
        #pragma unroll
        for (int j = 0; j < 4; j++) {
            int c = bn * 64 + tx * 4 + j;
            float v = acc[i][j] + rdIn(bv, c, f32);
            if (TANH) v = tanhf(v);
            v *= gate[(r >> SMPSHIFT) * Nd + c];
            Y[(long)r * Nd + c] = v;
        }
    }
}

// ===========================================================================
// output tail (fp32): [pos_skip_l0 (32768*3) | batch_skip_l0 (32768)]
// ===========================================================================
__global__ void fpno_tail(const void* __restrict__ pos0, const int* __restrict__ bt0,
                          const int* __restrict__ flagp, float* __restrict__ out) {
    const int f32 = *flagp;
    int id = blockIdx.x * 256 + threadIdx.x;  // 0..131071
    const int nX = kB * kN0 * kC0;   // 2097152
    const int nP = kB * kN0 * 3;     // 98304
    if (id < nP) out[nX + id] = rdIn(pos0, id, f32);
    else         out[nX + id] = (float)bt0[id - nP];
}

__global__ void fpno_guard(float code, float* __restrict__ out) {
    if (threadIdx.x == 0) out[0] = code;
}

// ===========================================================================
extern "C" void kernel_launch(void* const* d_in, const int* in_sizes, int n_in,
                              void* d_out, int out_size, void* d_ws, size_t ws_size,
                              hipStream_t stream) {
    (void)out_size;
    float* out = (float*)d_out;   // fp32 output buffer
    const int R1 = kB * kN1;  // 8192
    const int R0 = kB * kN0;  // 32768

    static const int kExp[22] = {
        256, 524288, 6144, 2048, 1048576, 24576, 8192, 2097152, 98304, 32768,
        98304, 256, 32768, 128, 8192, 128, 24576, 128, 8192, 64, 4096, 64};
    if (n_in != 22) { fpno_guard<<<1, 64, 0, stream>>>(3072.0f, out); return; }
    for (int i = 0; i < 22; i++) {
        if (in_sizes[i] != kExp[i]) {
            fpno_guard<<<1, 64, 0, stream>>>(1024.0f + 8.0f * i, out);
            return;
        }
    }

    // ---- fp32 workspace (~29.3 MB) ----
    char* base = (char*)d_ws;
    size_t off = 0;
    auto alloc = [&](size_t bytes) {
        off = (off + 255) & ~(size_t)255; size_t o = off; off += bytes; return o;
    };
    int*   flag = (int*)(base + alloc(4));
    float* g0   = (float*)(base + alloc(kB * 128 * 4));
    float* g1   = (float*)(base + alloc(kB * 64 * 4));
    int*   i1d  = (int*)(base + alloc((size_t)R1 * 3 * 4));
    float* w1d  = (float*)(base + alloc((size_t)R1 * 3 * 4));
    int*   i0d  = (int*)(base + alloc((size_t)R0 * 3 * 4));
    float* w0d  = (float*)(base + alloc((size_t)R0 * 3 * 4));
    float* H1   = (float*)(base + alloc((size_t)R1 * 256 * 4));  // 8 MB
    float* X1   = (float*)(base + alloc((size_t)R1 * 128 * 4));  // 4 MB
    float* H2   = (float*)(base + alloc((size_t)R0 * 128 * 4));  // 16 MB
    if (ws_size < off) { fpno_guard<<<1, 64, 0, stream>>>(2048.0f, out); return; }

    const void* par  = d_in[0];
    const void* x    = d_in[1];
    const void* pos  = d_in[2];
    const void* xs1  = d_in[4];
    const void* pos1 = d_in[5];
    const void* xs0  = d_in[7];
    const void* pos0 = d_in[8];
    const int*  bt0  = (const int*)d_in[9];
    const void *W0a = d_in[10], *b0a = d_in[11], *W0b = d_in[12], *b0b = d_in[13];
    const void *Wp0 = d_in[14], *bp0 = d_in[15];
    const void *W1a = d_in[16], *b1a = d_in[17], *W1b = d_in[18], *b1b = d_in[19];
    const void *Wp1 = d_in[20], *bp1 = d_in[21];

    // 1) input dtype probe
    fpno_probe_dtype<<<1, 256, 0, stream>>>((const unsigned int*)pos, flag);

    // 2) per-sample gates
    fpno_gates<<<3, 256, 0, stream>>>(par, Wp0, bp0, Wp1, bp1, flag, g0, g1);

    // 3) layer-1 kNN: src pos (512/s) -> tgt pos_skip_l1 (2048/s); 256 blocks
    fpno_nn3s<kN2><<<R1 / 32, 256, 0, stream>>>(pos, pos1, flag, kN1, i1d, w1d);

    // 4) H1 = tanh([interp(x), xs1] @ W0a + b0a)    8192x384 @ 384x256
    fpno_stage_a<kC2, kC1><<<dim3(R1 / 64, 4), 256, 0, stream>>>(
        x, nullptr, xs1, W0a, b0a, i1d, w1d, flag, H1, 256);

    // 5) X1 = tanh(H1 @ W0b + b0b) * g0             8192x256 @ 256x128, fp32
    fpno_stage_b<true, 11><<<dim3(R1 / 64, 2), 256, 0, stream>>>(
        H1, W0b, b0b, g0, flag, X1, 256, 128);

    // 6) layer-2 kNN: src pos_skip_l1 (2048/s) -> tgt pos_skip_l0 (8192/s); 1024 blocks
    fpno_nn3s<kN1><<<R0 / 32, 256, 0, stream>>>(pos1, pos0, flag, kN0, i0d, w0d);

    // 7) H2 = tanh([interp(X1), xs0] @ W1a + b1a)   32768x192 @ 192x128
    fpno_stage_a<kC1, kC0><<<dim3(R0 / 64, 2), 256, 0, stream>>>(
        nullptr, X1, xs0, W1a, b1a, i0d, w0d, flag, H2, 128);

    // 8) x0 = (H2 @ W1b + b1b) * g1 -> fp32 out     32768x128 @ 128x64
    fpno_stage_b<false, 13><<<dim3(R0 / 64, 1), 256, 0, stream>>>(
        H2, W1b, b1b, g1, flag, out, 128, 64);

    // 9) tail passthrough (fp32)
    fpno_tail<<<(kB * kN0 * 4) / 256, 256, 0, stream>>>(pos0, bt0, flag, out);
}